// Round 12
// baseline (3920.749 us; speedup 1.0000x reference)
//
#include <hip/hip_runtime.h>

#define NTOK 8192
#define HID 2048
#define ITR 7168
#define NE 8
#define BK32 32
#define TILE32 (128 * BK32)   // 4096 elems per 128x32 bf16 tile (8 KB)

typedef __attribute__((ext_vector_type(8))) short short8;
typedef __attribute__((ext_vector_type(8))) __bf16 bf16x8;
typedef __attribute__((ext_vector_type(4))) float f32x4;

__device__ __forceinline__ unsigned short f2bf(float f) {
  unsigned int u = __float_as_uint(f);
  u += 0x7FFFu + ((u >> 16) & 1u);   // round-to-nearest-even
  return (unsigned short)(u >> 16);
}

__device__ __forceinline__ f32x4 mfma_bf16(short8 a, short8 b, f32x4 c) {
  union U { short8 s; bf16x8 b; };
  U ua; ua.s = a;
  U ub; ub.s = b;
  return __builtin_amdgcn_mfma_f32_16x16x32_bf16(ua.b, ub.b, c, 0, 0, 0);
}

typedef __attribute__((address_space(1))) const unsigned int g_u32;
typedef __attribute__((address_space(3))) unsigned int l_u32;

// async global->LDS, 16B per lane; dst is wave-uniform base, src is per-lane
__device__ __forceinline__ void gload16(const unsigned short* src, unsigned short* dst) {
  __builtin_amdgcn_global_load_lds((g_u32*)src, (l_u32*)dst, 16, 0, 0);
}

// swizzled read: 16B slot index = (row*4 + c) ^ (row&7); valid for any row count
__device__ __forceinline__ short8 read_frag32(const unsigned short* base, int row, int kelem) {
  int slot = ((row << 2) + (kelem >> 3)) ^ (row & 7);
  return *reinterpret_cast<const short8*>(reinterpret_cast<const char*>(base) + slot * 16);
}

// inverse of the slot map: given linear slot s, which (row, chunk) must be loaded there
__device__ __forceinline__ void slot_src(int s, int* row, int* c) {
  int r0 = ((s >> 2) ^ (s >> 4)) & 1;
  *row = ((s >> 2) & ~1) | r0;
  *c = ((s ^ r0) & 1) | ((((s >> 1) ^ (s >> 3)) & 1) << 1);
}

// counted-vmcnt wait; never 0 mid-loop
#define VMCNT(N) asm volatile("s_waitcnt vmcnt(" #N ")" ::: "memory")
#define BARRIER()                         \
  do {                                    \
    __builtin_amdgcn_s_barrier();         \
    asm volatile("" ::: "memory");        \
  } while (0)

// ---------------- router: logits -> top2 -> pair lists + per-token pair ids ----------------
__global__ __launch_bounds__(256) void moe_router(
    const float* __restrict__ x, const float* __restrict__ gw,
    int* __restrict__ cnt, int* __restrict__ pair_token, float* __restrict__ pair_w,
    int4* __restrict__ tok_ep) {
  int wave = threadIdx.x >> 6;
  int lane = threadIdx.x & 63;
  int t = blockIdx.x * 4 + wave;
  const float4* xr = reinterpret_cast<const float4*>(x + (size_t)t * HID);
  float acc[NE];
#pragma unroll
  for (int e = 0; e < NE; ++e) acc[e] = 0.f;
#pragma unroll
  for (int j = 0; j < 8; ++j) {
    int c = lane + 64 * j;
    float4 xv = xr[c];
#pragma unroll
    for (int e = 0; e < NE; ++e) {
      float4 gv = reinterpret_cast<const float4*>(gw + (size_t)e * HID)[c];
      acc[e] += xv.x * gv.x + xv.y * gv.y + xv.z * gv.z + xv.w * gv.w;
    }
  }
#pragma unroll
  for (int e = 0; e < NE; ++e) {
    float s = acc[e];
#pragma unroll
    for (int m = 32; m > 0; m >>= 1) s += __shfl_xor(s, m);
    acc[e] = s;
  }
  if (lane == 0) {
    int e0 = 0; float l0 = acc[0];
#pragma unroll
    for (int e = 1; e < NE; ++e) if (acc[e] > l0) { l0 = acc[e]; e0 = e; }
    int e1 = -1; float l1 = -3.0e38f;
#pragma unroll
    for (int e = 0; e < NE; ++e) if (e != e0 && acc[e] > l1) { l1 = acc[e]; e1 = e; }
    float z = __expf(l1 - l0);
    float w0 = 1.f / (1.f + z);
    float w1 = z / (1.f + z);
    int p0 = atomicAdd(&cnt[e0], 1);
    pair_token[e0 * NTOK + p0] = t;
    pair_w[e0 * NTOK + p0] = w0;
    int p1 = atomicAdd(&cnt[e1], 1);
    pair_token[e1 * NTOK + p1] = t;
    pair_w[e1 * NTOK + p1] = w1;
    tok_ep[t] = make_int4(e0, e1, p0, p1);
  }
}

__global__ void moe_scan(const int* __restrict__ cnt, int* __restrict__ base) {
  if (threadIdx.x == 0) {
    int s = 0;
#pragma unroll
    for (int e = 0; e < NE; ++e) { base[e] = s; s += cnt[e]; }
  }
}

// ---------------- fp32 -> bf16 bulk convert (8 elems/thread, exact grids) ----------------
__global__ __launch_bounds__(256) void moe_cvt(const float* __restrict__ src,
                                               unsigned short* __restrict__ dst) {
  size_t i = (size_t)blockIdx.x * 256 + threadIdx.x;
  const float4* p = reinterpret_cast<const float4*>(src) + i * 2;
  float4 a = p[0], b = p[1];
  union { unsigned short us[8]; short8 v; } u;
  u.us[0] = f2bf(a.x); u.us[1] = f2bf(a.y); u.us[2] = f2bf(a.z); u.us[3] = f2bf(a.w);
  u.us[4] = f2bf(b.x); u.us[5] = f2bf(b.y); u.us[6] = f2bf(b.z); u.us[7] = f2bf(b.w);
  reinterpret_cast<short8*>(dst)[i] = u.v;
}

// ==== round-7 T4 pipeline: ring-3 LDS, {vmcnt -> barrier -> compute -> stage} ====

// GEMM1: g = silu(x@w1^T) * (x@w3^T)   [verbatim round-7 moe_gemm1_e — control]
__global__ __launch_bounds__(256, 2) void moe_gemm1_e(
    const unsigned short* __restrict__ xb, const unsigned short* __restrict__ w1b,
    const unsigned short* __restrict__ w3b, const int* __restrict__ cnt,
    const int* __restrict__ base, const int* __restrict__ pair_token,
    unsigned short* __restrict__ g) {
  int e = blockIdx.z;
  int n_e = cnt[e];
  int rowTile = blockIdx.x;
  if (rowTile * 128 >= n_e) return;
  int colTile = blockIdx.y;

  __shared__ unsigned short lds[3 * 3 * TILE32];   // 72 KB: ring-3 x {A,B1,B3} -> 2 blk/CU

  int tid = threadIdx.x;
  int lane = tid & 63;
  int wv = tid >> 6;
  int wr = wv >> 1, wc = wv & 1;
  int lr = lane & 15;
  int lk = (lane >> 4) * 8;

  int slotP = e * NTOK + rowTile * 128;
  int slotG = base[e] + rowTile * 128;
  const unsigned short* w1e = w1b + (size_t)e * ITR * HID + (size_t)colTile * 128 * HID;
  const unsigned short* w3e = w3b + (size_t)e * ITR * HID + (size_t)colTile * 128 * HID;

  const unsigned short* a_s[2];
  const unsigned short* b1_s[2];
  const unsigned short* b3_s[2];
#pragma unroll
  for (int i = 0; i < 2; ++i) {
    int s = wv * 128 + i * 64 + lane;     // 16B-slot index within 512-slot tile
    int row, c;
    slot_src(s, &row, &c);
    int tok = pair_token[slotP + ((rowTile * 128 + row < n_e) ? row : 0)];
    a_s[i] = xb + (size_t)tok * HID + c * 8;
    b1_s[i] = w1e + (size_t)row * HID + c * 8;
    b3_s[i] = w3e + (size_t)row * HID + c * 8;
  }

  f32x4 acc1[4][4], acc3[4][4];
#pragma unroll
  for (int m = 0; m < 4; ++m)
#pragma unroll
    for (int n = 0; n < 4; ++n) {
      acc1[m][n] = (f32x4){0.f, 0.f, 0.f, 0.f};
      acc3[m][n] = (f32x4){0.f, 0.f, 0.f, 0.f};
    }

#define STAGE1(buf, koff)                                                        \
  do {                                                                           \
    unsigned short* Lb = lds + (buf) * 3 * TILE32 + wv * 1024;                   \
    _Pragma("unroll") for (int i = 0; i < 2; ++i) {                              \
      gload16(a_s[i] + (koff), Lb + i * 512);                                    \
      gload16(b1_s[i] + (koff), Lb + TILE32 + i * 512);                          \
      gload16(b3_s[i] + (koff), Lb + 2 * TILE32 + i * 512);                      \
    }                                                                            \
  } while (0)

  const int nt = HID / BK32;   // 64
  STAGE1(0, 0);
  STAGE1(1, BK32);

  for (int t = 0; t < nt; ++t) {
    if (t + 1 < nt) VMCNT(6); else VMCNT(0);
    BARRIER();

    const unsigned short* A = lds + (t % 3) * 3 * TILE32;
    const unsigned short* B1 = A + TILE32;
    const unsigned short* B3 = A + 2 * TILE32;
    short8 av[4];
#pragma unroll
    for (int m = 0; m < 4; ++m) av[m] = read_frag32(A, wr * 64 + m * 16 + lr, lk);
#pragma unroll
    for (int n = 0; n < 4; ++n) {
      short8 b1v = read_frag32(B1, wc * 64 + n * 16 + lr, lk);
      short8 b3v = read_frag32(B3, wc * 64 + n * 16 + lr, lk);
#pragma unroll
      for (int m = 0; m < 4; ++m) {
        acc1[m][n] = mfma_bf16(av[m], b1v, acc1[m][n]);
        acc3[m][n] = mfma_bf16(av[m], b3v, acc3[m][n]);
      }
    }

    if (t + 2 < nt) STAGE1((t + 2) % 3, (t + 2) * BK32);
  }
#undef STAGE1

#pragma unroll
  for (int m = 0; m < 4; ++m) {
    int rbase = wr * 64 + m * 16 + ((lane >> 4) << 2);
#pragma unroll
    for (int r = 0; r < 4; ++r) {
      int rt = rbase + r;
      if (rowTile * 128 + rt < n_e) {
        unsigned short* grow = g + (size_t)(slotG + rt) * ITR + colTile * 128 + wc * 64;
#pragma unroll
        for (int n = 0; n < 4; ++n) {
          float h1 = acc1[m][n][r], h3 = acc3[m][n][r];
          float sl = h1 / (1.f + __expf(-h1));
          grow[n * 16 + lr] = f2bf(sl * h3);
        }
      }
    }
  }
}

// GEMM2: part[slot] = w * (g[slot] @ w2^T)
// Re-tiled: 256x128 block, 4 waves of 128x64 (m=8,n=4) -> 0.023 LDS B/MAC (was 0.031)
#define G2H_BUF 12288   // shorts per ring slot: A(256x32=8192) + B(128x32=4096)

__global__ __launch_bounds__(256, 2) void moe_gemm2_h(
    const unsigned short* __restrict__ g, const unsigned short* __restrict__ w2b,
    const int* __restrict__ cnt, const int* __restrict__ base,
    const float* __restrict__ pair_w, float* __restrict__ part) {
  int e = blockIdx.z;
  int n_e = cnt[e];
  int rowTile = blockIdx.x;
  if (rowTile * 256 >= n_e) return;
  int colTile = blockIdx.y;

  __shared__ unsigned short lds[3 * G2H_BUF];   // 72 KB: ring-3 -> 2 blk/CU

  int tid = threadIdx.x;
  int lane = tid & 63;
  int wv = tid >> 6;
  int wr = wv >> 1;            // 0..1: 128-row band
  int wc = wv & 1;             // 0..1: 64-col band
  int lr = lane & 15;
  int lk = (lane >> 4) * 8;

  int slotP = e * NTOK + rowTile * 256;
  int slotG = base[e] + rowTile * 256;
  const unsigned short* w2e = w2b + (size_t)e * HID * ITR + (size_t)colTile * 128 * ITR;

  // A: 1024 slots (256 rows x 4 chunks); B: 512 slots (128 rows x 4 chunks)
  const unsigned short* a_s[4];
  const unsigned short* b_s[2];
#pragma unroll
  for (int i = 0; i < 4; ++i) {
    int s = wv * 256 + i * 64 + lane;
    int row, c;
    slot_src(s, &row, &c);
    int rclamp = (rowTile * 256 + row < n_e) ? row : 0;
    a_s[i] = g + (size_t)(slotG + rclamp) * ITR + c * 8;   // g rows compact -> dense
  }
#pragma unroll
  for (int i = 0; i < 2; ++i) {
    int s = wv * 128 + i * 64 + lane;
    int row, c;
    slot_src(s, &row, &c);
    b_s[i] = w2e + (size_t)row * ITR + c * 8;
  }

  f32x4 acc[8][4];
#pragma unroll
  for (int m = 0; m < 8; ++m)
#pragma unroll
    for (int n = 0; n < 4; ++n) acc[m][n] = (f32x4){0.f, 0.f, 0.f, 0.f};

#define STAGE2(buf, koff)                                                        \
  do {                                                                           \
    unsigned short* Lb = lds + (buf) * G2H_BUF;                                  \
    _Pragma("unroll") for (int i = 0; i < 4; ++i)                                \
      gload16(a_s[i] + (koff), Lb + wv * 2048 + i * 512);                        \
    _Pragma("unroll") for (int i = 0; i < 2; ++i)                                \
      gload16(b_s[i] + (koff), Lb + 8192 + wv * 1024 + i * 512);                 \
  } while (0)

  const int nt = ITR / BK32;   // 224
  STAGE2(0, 0);
  STAGE2(1, BK32);

  for (int t = 0; t < nt; ++t) {
    // outstanding {S(t),S(t+1)} = 12 loads -> vmcnt(6) lands S(t), S(t+1) stays in flight
    if (t + 1 < nt) VMCNT(6); else VMCNT(0);
    BARRIER();

    const unsigned short* A = lds + (t % 3) * G2H_BUF;
    const unsigned short* B = A + 8192;
    short8 av[8];
#pragma unroll
    for (int m = 0; m < 8; ++m) av[m] = read_frag32(A, wr * 128 + m * 16 + lr, lk);
#pragma unroll
    for (int n = 0; n < 4; ++n) {
      short8 bv = read_frag32(B, wc * 64 + n * 16 + lr, lk);
#pragma unroll
      for (int m = 0; m < 8; ++m) acc[m][n] = mfma_bf16(av[m], bv, acc[m][n]);
    }

    if (t + 2 < nt) STAGE2((t + 2) % 3, (t + 2) * BK32);
  }
#undef STAGE2

#pragma unroll
  for (int m = 0; m < 8; ++m) {
    int rbase = wr * 128 + m * 16 + ((lane >> 4) << 2);
#pragma unroll
    for (int r = 0; r < 4; ++r) {
      int rt = rbase + r;
      if (rowTile * 256 + rt < n_e) {
        float wgt = pair_w[slotP + rt];
        float* prow = part + (size_t)(slotG + rt) * HID + colTile * 128 + wc * 64;
#pragma unroll
        for (int n = 0; n < 4; ++n) prow[n * 16 + lr] = wgt * acc[m][n][r];
      }
    }
  }
}

// ---------------- combine: out[t] = part[slot0] + part[slot1] ----------------
__global__ __launch_bounds__(256) void moe_combine(
    const float* __restrict__ part, const int4* __restrict__ tok_ep,
    const int* __restrict__ base, float* __restrict__ out) {
  int t = blockIdx.x;
  int4 ep = tok_ep[t];
  int s0 = base[ep.x] + ep.z;
  int s1 = base[ep.y] + ep.w;
  const float4* p0 = reinterpret_cast<const float4*>(part + (size_t)s0 * HID);
  const float4* p1 = reinterpret_cast<const float4*>(part + (size_t)s1 * HID);
  float4* o = reinterpret_cast<float4*>(out + (size_t)t * HID);
#pragma unroll
  for (int i = 0; i < 2; ++i) {
    int idx = threadIdx.x + i * 256;    // 512 float4 per row
    float4 a = p0[idx], b = p1[idx];
    o[idx] = make_float4(a.x + b.x, a.y + b.y, a.z + b.z, a.w + b.w);
  }
}

// ================= launch =================

extern "C" void kernel_launch(void* const* d_in, const int* in_sizes, int n_in,
                              void* d_out, int out_size, void* d_ws, size_t ws_size,
                              hipStream_t stream) {
  const float* x = (const float*)d_in[0];
  const float* gate_w = (const float*)d_in[1];
  const float* w1 = (const float*)d_in[2];
  const float* w3 = (const float*)d_in[3];
  const float* w2 = (const float*)d_in[4];
  float* out = (float*)d_out;

  char* ws = (char*)d_ws;
  const size_t WEL = (size_t)NE * ITR * HID;                 // elems per weight tensor
  const size_t G_BYTES = (size_t)NTOK * 2 * ITR * 2;         // 16384 x 7168 bf16
  const size_t XB_BYTES = (size_t)NTOK * HID * 2;
  const size_t PAIR_BYTES = (size_t)NE * NTOK * 4;
  const size_t TOKEP_BYTES = (size_t)NTOK * 16;
  const size_t WB_BYTES = WEL * 2;                           // one bf16 weight tensor

  unsigned short* g = (unsigned short*)ws;
  unsigned short* xb = (unsigned short*)(ws + G_BYTES);
  int* pair_token = (int*)(ws + G_BYTES + XB_BYTES);
  float* pair_w = (float*)(ws + G_BYTES + XB_BYTES + PAIR_BYTES);
  int4* tok_ep = (int4*)(ws + G_BYTES + XB_BYTES + 2 * PAIR_BYTES);
  int* cnt = (int*)(ws + G_BYTES + XB_BYTES + 2 * PAIR_BYTES + TOKEP_BYTES);
  int* base = cnt + NE;
  char* wbase = ws + G_BYTES + XB_BYTES + 2 * PAIR_BYTES + TOKEP_BYTES + 256;
  unsigned short* w1b = (unsigned short*)wbase;
  unsigned short* w3b = (unsigned short*)(wbase + WB_BYTES);
  unsigned short* w2b = (unsigned short*)(wbase + 2 * WB_BYTES);
  float* part = (float*)wbase;   // aliases w1b: dead after gemm1, reused by gemm2

  hipMemsetAsync(cnt, 0, 2 * NE * sizeof(int), stream);

  moe_router<<<NTOK / 4, 256, 0, stream>>>(x, gate_w, cnt, pair_token, pair_w, tok_ep);
  moe_scan<<<1, 64, 0, stream>>>(cnt, base);
  moe_cvt<<<(NTOK * HID) / 2048, 256, 0, stream>>>(x, xb);

  const int WGRID = (int)(WEL / 2048);                       // 57344
  moe_cvt<<<WGRID, 256, 0, stream>>>(w1, w1b);
  moe_cvt<<<WGRID, 256, 0, stream>>>(w3, w3b);
  moe_cvt<<<WGRID, 256, 0, stream>>>(w2, w2b);

  moe_gemm1_e<<<dim3(NTOK / 128, ITR / 128, NE), 256, 0, stream>>>(
      xb, w1b, w3b, cnt, base, pair_token, g);
  moe_gemm2_h<<<dim3(NTOK / 256, HID / 128, NE), 256, 0, stream>>>(
      g, w2b, cnt, base, pair_w, part);
  moe_combine<<<NTOK, 256, 0, stream>>>(part, tok_ep, base, out);
}

// Round 13
// 3397.813 us; speedup vs baseline: 1.1539x; 1.1539x over previous
//
#include <hip/hip_runtime.h>

#define NTOK 8192
#define HID 2048
#define ITR 7168
#define NE 8
#define BK32 32
#define TILE32 (128 * BK32)   // 4096 elems per 128x32 bf16 tile (8 KB)

typedef __attribute__((ext_vector_type(8))) short short8;
typedef __attribute__((ext_vector_type(8))) __bf16 bf16x8;
typedef __attribute__((ext_vector_type(4))) float f32x4;

__device__ __forceinline__ unsigned short f2bf(float f) {
  unsigned int u = __float_as_uint(f);
  u += 0x7FFFu + ((u >> 16) & 1u);   // round-to-nearest-even
  return (unsigned short)(u >> 16);
}

__device__ __forceinline__ f32x4 mfma_bf16(short8 a, short8 b, f32x4 c) {
  union U { short8 s; bf16x8 b; };
  U ua; ua.s = a;
  U ub; ub.s = b;
  return __builtin_amdgcn_mfma_f32_16x16x32_bf16(ua.b, ub.b, c, 0, 0, 0);
}

typedef __attribute__((address_space(1))) const unsigned int g_u32;
typedef __attribute__((address_space(3))) unsigned int l_u32;

// async global->LDS, 16B per lane; dst is wave-uniform base, src is per-lane
__device__ __forceinline__ void gload16(const unsigned short* src, unsigned short* dst) {
  __builtin_amdgcn_global_load_lds((g_u32*)src, (l_u32*)dst, 16, 0, 0);
}

// swizzled read: 16B slot index = (row*4 + c) ^ (row&7)
__device__ __forceinline__ short8 read_frag32(const unsigned short* base, int row, int kelem) {
  int slot = ((row << 2) + (kelem >> 3)) ^ (row & 7);
  return *reinterpret_cast<const short8*>(reinterpret_cast<const char*>(base) + slot * 16);
}

// inverse of the slot map: given linear slot s, which (row, chunk) must be loaded there
__device__ __forceinline__ void slot_src(int s, int* row, int* c) {
  int r0 = ((s >> 2) ^ (s >> 4)) & 1;
  *row = ((s >> 2) & ~1) | r0;
  *c = ((s ^ r0) & 1) | ((((s >> 1) ^ (s >> 3)) & 1) << 1);
}

// counted-vmcnt wait; never 0 mid-loop
#define VMCNT(N) asm volatile("s_waitcnt vmcnt(" #N ")" ::: "memory")
#define BARRIER()                         \
  do {                                    \
    __builtin_amdgcn_s_barrier();         \
    asm volatile("" ::: "memory");        \
  } while (0)

// ---------------- router: logits -> top2 -> pair lists + per-token pair ids ----------------
__global__ __launch_bounds__(256) void moe_router(
    const float* __restrict__ x, const float* __restrict__ gw,
    int* __restrict__ cnt, int* __restrict__ pair_token, float* __restrict__ pair_w,
    int4* __restrict__ tok_ep) {
  int wave = threadIdx.x >> 6;
  int lane = threadIdx.x & 63;
  int t = blockIdx.x * 4 + wave;
  const float4* xr = reinterpret_cast<const float4*>(x + (size_t)t * HID);
  float acc[NE];
#pragma unroll
  for (int e = 0; e < NE; ++e) acc[e] = 0.f;
#pragma unroll
  for (int j = 0; j < 8; ++j) {
    int c = lane + 64 * j;
    float4 xv = xr[c];
#pragma unroll
    for (int e = 0; e < NE; ++e) {
      float4 gv = reinterpret_cast<const float4*>(gw + (size_t)e * HID)[c];
      acc[e] += xv.x * gv.x + xv.y * gv.y + xv.z * gv.z + xv.w * gv.w;
    }
  }
#pragma unroll
  for (int e = 0; e < NE; ++e) {
    float s = acc[e];
#pragma unroll
    for (int m = 32; m > 0; m >>= 1) s += __shfl_xor(s, m);
    acc[e] = s;
  }
  if (lane == 0) {
    int e0 = 0; float l0 = acc[0];
#pragma unroll
    for (int e = 1; e < NE; ++e) if (acc[e] > l0) { l0 = acc[e]; e0 = e; }
    int e1 = -1; float l1 = -3.0e38f;
#pragma unroll
    for (int e = 0; e < NE; ++e) if (e != e0 && acc[e] > l1) { l1 = acc[e]; e1 = e; }
    float z = __expf(l1 - l0);
    float w0 = 1.f / (1.f + z);
    float w1 = z / (1.f + z);
    int p0 = atomicAdd(&cnt[e0], 1);
    pair_token[e0 * NTOK + p0] = t;
    pair_w[e0 * NTOK + p0] = w0;
    int p1 = atomicAdd(&cnt[e1], 1);
    pair_token[e1 * NTOK + p1] = t;
    pair_w[e1 * NTOK + p1] = w1;
    tok_ep[t] = make_int4(e0, e1, p0, p1);
  }
}

__global__ void moe_scan(const int* __restrict__ cnt, int* __restrict__ base) {
  if (threadIdx.x == 0) {
    int s = 0;
#pragma unroll
    for (int e = 0; e < NE; ++e) { base[e] = s; s += cnt[e]; }
  }
}

// ---------------- fp32 -> bf16 bulk convert (8 elems/thread, exact grids) ----------------
__global__ __launch_bounds__(256) void moe_cvt(const float* __restrict__ src,
                                               unsigned short* __restrict__ dst) {
  size_t i = (size_t)blockIdx.x * 256 + threadIdx.x;
  const float4* p = reinterpret_cast<const float4*>(src) + i * 2;
  float4 a = p[0], b = p[1];
  union { unsigned short us[8]; short8 v; } u;
  u.us[0] = f2bf(a.x); u.us[1] = f2bf(a.y); u.us[2] = f2bf(a.z); u.us[3] = f2bf(a.w);
  u.us[4] = f2bf(b.x); u.us[5] = f2bf(b.y); u.us[6] = f2bf(b.z); u.us[7] = f2bf(b.w);
  reinterpret_cast<short8*>(dst)[i] = u.v;
}

// ==== round-9 T4 pipeline + T5 setprio: ring-3 LDS, {vmcnt -> barrier -> prio1 compute prio0 -> stage} ====

// GEMM1: g = silu(x@w1^T) * (x@w3^T)
__global__ __launch_bounds__(256, 2) void moe_gemm1_e(
    const unsigned short* __restrict__ xb, const unsigned short* __restrict__ w1b,
    const unsigned short* __restrict__ w3b, const int* __restrict__ cnt,
    const int* __restrict__ base, const int* __restrict__ pair_token,
    unsigned short* __restrict__ g) {
  int e = blockIdx.z;
  int n_e = cnt[e];
  int rowTile = blockIdx.x;
  if (rowTile * 128 >= n_e) return;
  int colTile = blockIdx.y;

  __shared__ unsigned short lds[3 * 3 * TILE32];   // 72 KB: ring-3 x {A,B1,B3} -> 2 blk/CU

  int tid = threadIdx.x;
  int lane = tid & 63;
  int wv = tid >> 6;
  int wr = wv >> 1, wc = wv & 1;
  int lr = lane & 15;
  int lk = (lane >> 4) * 8;

  int slotP = e * NTOK + rowTile * 128;
  int slotG = base[e] + rowTile * 128;
  const unsigned short* w1e = w1b + (size_t)e * ITR * HID + (size_t)colTile * 128 * HID;
  const unsigned short* w3e = w3b + (size_t)e * ITR * HID + (size_t)colTile * 128 * HID;

  const unsigned short* a_s[2];
  const unsigned short* b1_s[2];
  const unsigned short* b3_s[2];
#pragma unroll
  for (int i = 0; i < 2; ++i) {
    int s = wv * 128 + i * 64 + lane;     // 16B-slot index within 512-slot tile
    int row, c;
    slot_src(s, &row, &c);
    int tok = pair_token[slotP + ((rowTile * 128 + row < n_e) ? row : 0)];
    a_s[i] = xb + (size_t)tok * HID + c * 8;
    b1_s[i] = w1e + (size_t)row * HID + c * 8;
    b3_s[i] = w3e + (size_t)row * HID + c * 8;
  }

  f32x4 acc1[4][4], acc3[4][4];
#pragma unroll
  for (int m = 0; m < 4; ++m)
#pragma unroll
    for (int n = 0; n < 4; ++n) {
      acc1[m][n] = (f32x4){0.f, 0.f, 0.f, 0.f};
      acc3[m][n] = (f32x4){0.f, 0.f, 0.f, 0.f};
    }

#define STAGE1(buf, koff)                                                        \
  do {                                                                           \
    unsigned short* Lb = lds + (buf) * 3 * TILE32 + wv * 1024;                   \
    _Pragma("unroll") for (int i = 0; i < 2; ++i) {                              \
      gload16(a_s[i] + (koff), Lb + i * 512);                                    \
      gload16(b1_s[i] + (koff), Lb + TILE32 + i * 512);                          \
      gload16(b3_s[i] + (koff), Lb + 2 * TILE32 + i * 512);                      \
    }                                                                            \
  } while (0)

  const int nt = HID / BK32;   // 64
  STAGE1(0, 0);
  STAGE1(1, BK32);

  for (int t = 0; t < nt; ++t) {
    if (t + 1 < nt) VMCNT(6); else VMCNT(0);
    BARRIER();

    __builtin_amdgcn_s_setprio(1);   // T5: favor compute-phase waves on the CU scheduler
    const unsigned short* A = lds + (t % 3) * 3 * TILE32;
    const unsigned short* B1 = A + TILE32;
    const unsigned short* B3 = A + 2 * TILE32;
    short8 av[4];
#pragma unroll
    for (int m = 0; m < 4; ++m) av[m] = read_frag32(A, wr * 64 + m * 16 + lr, lk);
#pragma unroll
    for (int n = 0; n < 4; ++n) {
      short8 b1v = read_frag32(B1, wc * 64 + n * 16 + lr, lk);
      short8 b3v = read_frag32(B3, wc * 64 + n * 16 + lr, lk);
#pragma unroll
      for (int m = 0; m < 4; ++m) {
        acc1[m][n] = mfma_bf16(av[m], b1v, acc1[m][n]);
        acc3[m][n] = mfma_bf16(av[m], b3v, acc3[m][n]);
      }
    }
    __builtin_amdgcn_s_setprio(0);

    if (t + 2 < nt) STAGE1((t + 2) % 3, (t + 2) * BK32);
  }
#undef STAGE1

#pragma unroll
  for (int m = 0; m < 4; ++m) {
    int rbase = wr * 64 + m * 16 + ((lane >> 4) << 2);
#pragma unroll
    for (int r = 0; r < 4; ++r) {
      int rt = rbase + r;
      if (rowTile * 128 + rt < n_e) {
        unsigned short* grow = g + (size_t)(slotG + rt) * ITR + colTile * 128 + wc * 64;
#pragma unroll
        for (int n = 0; n < 4; ++n) {
          float h1 = acc1[m][n][r], h3 = acc3[m][n][r];
          float sl = h1 / (1.f + __expf(-h1));
          grow[n * 16 + lr] = f2bf(sl * h3);
        }
      }
    }
  }
}

// GEMM2: part[slot] = w * (g[slot] @ w2^T)  — round-9 proven geometry + T5
__global__ __launch_bounds__(256, 3) void moe_gemm2_g(
    const unsigned short* __restrict__ g, const unsigned short* __restrict__ w2b,
    const int* __restrict__ cnt, const int* __restrict__ base,
    const float* __restrict__ pair_w, float* __restrict__ part) {
  int e = blockIdx.z;
  int n_e = cnt[e];
  int rowTile = blockIdx.x;
  if (rowTile * 128 >= n_e) return;
  int colTile = blockIdx.y;

  __shared__ unsigned short lds[3 * 2 * TILE32];   // 48 KB: ring-3 x {A,B} -> 3 blk/CU

  int tid = threadIdx.x;
  int lane = tid & 63;
  int wv = tid >> 6;
  int wr = wv >> 1, wc = wv & 1;
  int lr = lane & 15;
  int lk = (lane >> 4) * 8;

  int slotP = e * NTOK + rowTile * 128;
  int slotG = base[e] + rowTile * 128;
  const unsigned short* w2e = w2b + (size_t)e * HID * ITR + (size_t)colTile * 128 * ITR;

  const unsigned short* a_s[2];
  const unsigned short* b_s[2];
#pragma unroll
  for (int i = 0; i < 2; ++i) {
    int s = wv * 128 + i * 64 + lane;
    int row, c;
    slot_src(s, &row, &c);
    int rclamp = (rowTile * 128 + row < n_e) ? row : 0;
    a_s[i] = g + (size_t)(slotG + rclamp) * ITR + c * 8;   // g rows compact -> dense
    b_s[i] = w2e + (size_t)row * ITR + c * 8;
  }

  f32x4 acc[4][4];
#pragma unroll
  for (int m = 0; m < 4; ++m)
#pragma unroll
    for (int n = 0; n < 4; ++n) acc[m][n] = (f32x4){0.f, 0.f, 0.f, 0.f};

#define STAGE2(buf, koff)                                                        \
  do {                                                                           \
    unsigned short* Lb = lds + (buf) * 2 * TILE32 + wv * 1024;                   \
    _Pragma("unroll") for (int i = 0; i < 2; ++i) {                              \
      gload16(a_s[i] + (koff), Lb + i * 512);                                    \
      gload16(b_s[i] + (koff), Lb + TILE32 + i * 512);                           \
    }                                                                            \
  } while (0)

  const int nt = ITR / BK32;   // 224
  STAGE2(0, 0);
  STAGE2(1, BK32);

  for (int t = 0; t < nt; ++t) {
    if (t + 1 < nt) VMCNT(4); else VMCNT(0);
    BARRIER();

    __builtin_amdgcn_s_setprio(1);
    const unsigned short* A = lds + (t % 3) * 2 * TILE32;
    const unsigned short* B = A + TILE32;
    short8 av[4];
#pragma unroll
    for (int m = 0; m < 4; ++m) av[m] = read_frag32(A, wr * 64 + m * 16 + lr, lk);
#pragma unroll
    for (int n = 0; n < 4; ++n) {
      short8 bv = read_frag32(B, wc * 64 + n * 16 + lr, lk);
#pragma unroll
      for (int m = 0; m < 4; ++m) acc[m][n] = mfma_bf16(av[m], bv, acc[m][n]);
    }
    __builtin_amdgcn_s_setprio(0);

    if (t + 2 < nt) STAGE2((t + 2) % 3, (t + 2) * BK32);
  }
#undef STAGE2

#pragma unroll
  for (int m = 0; m < 4; ++m) {
    int rbase = wr * 64 + m * 16 + ((lane >> 4) << 2);
#pragma unroll
    for (int r = 0; r < 4; ++r) {
      int rt = rbase + r;
      if (rowTile * 128 + rt < n_e) {
        float wgt = pair_w[slotP + rt];
        float* prow = part + (size_t)(slotG + rt) * HID + colTile * 128 + wc * 64;
#pragma unroll
        for (int n = 0; n < 4; ++n) prow[n * 16 + lr] = wgt * acc[m][n][r];
      }
    }
  }
}

// ---------------- combine: out[t] = part[slot0] + part[slot1] ----------------
__global__ __launch_bounds__(256) void moe_combine(
    const float* __restrict__ part, const int4* __restrict__ tok_ep,
    const int* __restrict__ base, float* __restrict__ out) {
  int t = blockIdx.x;
  int4 ep = tok_ep[t];
  int s0 = base[ep.x] + ep.z;
  int s1 = base[ep.y] + ep.w;
  const float4* p0 = reinterpret_cast<const float4*>(part + (size_t)s0 * HID);
  const float4* p1 = reinterpret_cast<const float4*>(part + (size_t)s1 * HID);
  float4* o = reinterpret_cast<float4*>(out + (size_t)t * HID);
#pragma unroll
  for (int i = 0; i < 2; ++i) {
    int idx = threadIdx.x + i * 256;    // 512 float4 per row
    float4 a = p0[idx], b = p1[idx];
    o[idx] = make_float4(a.x + b.x, a.y + b.y, a.z + b.z, a.w + b.w);
  }
}

// ================= launch =================

extern "C" void kernel_launch(void* const* d_in, const int* in_sizes, int n_in,
                              void* d_out, int out_size, void* d_ws, size_t ws_size,
                              hipStream_t stream) {
  const float* x = (const float*)d_in[0];
  const float* gate_w = (const float*)d_in[1];
  const float* w1 = (const float*)d_in[2];
  const float* w3 = (const float*)d_in[3];
  const float* w2 = (const float*)d_in[4];
  float* out = (float*)d_out;

  char* ws = (char*)d_ws;
  const size_t WEL = (size_t)NE * ITR * HID;                 // elems per weight tensor
  const size_t G_BYTES = (size_t)NTOK * 2 * ITR * 2;         // 16384 x 7168 bf16
  const size_t XB_BYTES = (size_t)NTOK * HID * 2;
  const size_t PAIR_BYTES = (size_t)NE * NTOK * 4;
  const size_t TOKEP_BYTES = (size_t)NTOK * 16;
  const size_t WB_BYTES = WEL * 2;                           // one bf16 weight tensor

  unsigned short* g = (unsigned short*)ws;
  unsigned short* xb = (unsigned short*)(ws + G_BYTES);
  int* pair_token = (int*)(ws + G_BYTES + XB_BYTES);
  float* pair_w = (float*)(ws + G_BYTES + XB_BYTES + PAIR_BYTES);
  int4* tok_ep = (int4*)(ws + G_BYTES + XB_BYTES + 2 * PAIR_BYTES);
  int* cnt = (int*)(ws + G_BYTES + XB_BYTES + 2 * PAIR_BYTES + TOKEP_BYTES);
  int* base = cnt + NE;
  char* wbase = ws + G_BYTES + XB_BYTES + 2 * PAIR_BYTES + TOKEP_BYTES + 256;
  unsigned short* w1b = (unsigned short*)wbase;
  unsigned short* w3b = (unsigned short*)(wbase + WB_BYTES);
  unsigned short* w2b = (unsigned short*)(wbase + 2 * WB_BYTES);
  float* part = (float*)wbase;   // aliases w1b: dead after gemm1, reused by gemm2

  hipMemsetAsync(cnt, 0, 2 * NE * sizeof(int), stream);

  moe_router<<<NTOK / 4, 256, 0, stream>>>(x, gate_w, cnt, pair_token, pair_w, tok_ep);
  moe_scan<<<1, 64, 0, stream>>>(cnt, base);
  moe_cvt<<<(NTOK * HID) / 2048, 256, 0, stream>>>(x, xb);

  const int WGRID = (int)(WEL / 2048);                       // 57344
  moe_cvt<<<WGRID, 256, 0, stream>>>(w1, w1b);
  moe_cvt<<<WGRID, 256, 0, stream>>>(w3, w3b);
  moe_cvt<<<WGRID, 256, 0, stream>>>(w2, w2b);

  moe_gemm1_e<<<dim3(NTOK / 128, ITR / 128, NE), 256, 0, stream>>>(
      xb, w1b, w3b, cnt, base, pair_token, g);
  moe_gemm2_g<<<dim3(NTOK / 128, HID / 128, NE), 256, 0, stream>>>(
      g, w2b, cnt, base, pair_w, part);
  moe_combine<<<NTOK, 256, 0, stream>>>(part, tok_ep, base, out);
}

// Round 14
// 3167.794 us; speedup vs baseline: 1.2377x; 1.0726x over previous
//
#include <hip/hip_runtime.h>

#define NTOK 8192
#define HID 2048
#define ITR 7168
#define NE 8
#define BK32 32
#define TILE32 (128 * BK32)   // 4096 elems per 128x32 bf16 tile (8 KB)

typedef __attribute__((ext_vector_type(8))) short short8;
typedef __attribute__((ext_vector_type(8))) __bf16 bf16x8;
typedef __attribute__((ext_vector_type(4))) float f32x4;

__device__ __forceinline__ unsigned short f2bf(float f) {
  unsigned int u = __float_as_uint(f);
  u += 0x7FFFu + ((u >> 16) & 1u);   // round-to-nearest-even
  return (unsigned short)(u >> 16);
}

__device__ __forceinline__ f32x4 mfma_bf16(short8 a, short8 b, f32x4 c) {
  union U { short8 s; bf16x8 b; };
  U ua; ua.s = a;
  U ub; ub.s = b;
  return __builtin_amdgcn_mfma_f32_16x16x32_bf16(ua.b, ub.b, c, 0, 0, 0);
}

typedef __attribute__((address_space(1))) const unsigned int g_u32;
typedef __attribute__((address_space(3))) unsigned int l_u32;

// async global->LDS, 16B per lane; dst is wave-uniform base, src is per-lane
__device__ __forceinline__ void gload16(const unsigned short* src, unsigned short* dst) {
  __builtin_amdgcn_global_load_lds((g_u32*)src, (l_u32*)dst, 16, 0, 0);
}

// swizzled read: 16B slot index = (row*4 + c) ^ (row&7)
__device__ __forceinline__ short8 read_frag32(const unsigned short* base, int row, int kelem) {
  int slot = ((row << 2) + (kelem >> 3)) ^ (row & 7);
  return *reinterpret_cast<const short8*>(reinterpret_cast<const char*>(base) + slot * 16);
}

// inverse of the slot map: given linear slot s, which (row, chunk) must be loaded there
__device__ __forceinline__ void slot_src(int s, int* row, int* c) {
  int r0 = ((s >> 2) ^ (s >> 4)) & 1;
  *row = ((s >> 2) & ~1) | r0;
  *c = ((s ^ r0) & 1) | ((((s >> 1) ^ (s >> 3)) & 1) << 1);
}

// counted-vmcnt wait; never 0 mid-loop
#define VMCNT(N) asm volatile("s_waitcnt vmcnt(" #N ")" ::: "memory")
#define BARRIER()                         \
  do {                                    \
    __builtin_amdgcn_s_barrier();         \
    asm volatile("" ::: "memory");        \
  } while (0)

// ---------------- router: logits -> top2 -> pair lists + per-token pair ids ----------------
__global__ __launch_bounds__(256) void moe_router(
    const float* __restrict__ x, const float* __restrict__ gw,
    int* __restrict__ cnt, int* __restrict__ pair_token, float* __restrict__ pair_w,
    int4* __restrict__ tok_ep) {
  int wave = threadIdx.x >> 6;
  int lane = threadIdx.x & 63;
  int t = blockIdx.x * 4 + wave;
  const float4* xr = reinterpret_cast<const float4*>(x + (size_t)t * HID);
  float acc[NE];
#pragma unroll
  for (int e = 0; e < NE; ++e) acc[e] = 0.f;
#pragma unroll
  for (int j = 0; j < 8; ++j) {
    int c = lane + 64 * j;
    float4 xv = xr[c];
#pragma unroll
    for (int e = 0; e < NE; ++e) {
      float4 gv = reinterpret_cast<const float4*>(gw + (size_t)e * HID)[c];
      acc[e] += xv.x * gv.x + xv.y * gv.y + xv.z * gv.z + xv.w * gv.w;
    }
  }
#pragma unroll
  for (int e = 0; e < NE; ++e) {
    float s = acc[e];
#pragma unroll
    for (int m = 32; m > 0; m >>= 1) s += __shfl_xor(s, m);
    acc[e] = s;
  }
  if (lane == 0) {
    int e0 = 0; float l0 = acc[0];
#pragma unroll
    for (int e = 1; e < NE; ++e) if (acc[e] > l0) { l0 = acc[e]; e0 = e; }
    int e1 = -1; float l1 = -3.0e38f;
#pragma unroll
    for (int e = 0; e < NE; ++e) if (e != e0 && acc[e] > l1) { l1 = acc[e]; e1 = e; }
    float z = __expf(l1 - l0);
    float w0 = 1.f / (1.f + z);
    float w1 = z / (1.f + z);
    int p0 = atomicAdd(&cnt[e0], 1);
    pair_token[e0 * NTOK + p0] = t;
    pair_w[e0 * NTOK + p0] = w0;
    int p1 = atomicAdd(&cnt[e1], 1);
    pair_token[e1 * NTOK + p1] = t;
    pair_w[e1 * NTOK + p1] = w1;
    tok_ep[t] = make_int4(e0, e1, p0, p1);
  }
}

__global__ void moe_scan(const int* __restrict__ cnt, int* __restrict__ base) {
  if (threadIdx.x == 0) {
    int s = 0;
#pragma unroll
    for (int e = 0; e < NE; ++e) { base[e] = s; s += cnt[e]; }
  }
}

// ---------------- fp32 -> bf16 bulk convert (8 elems/thread, exact grids) ----------------
__global__ __launch_bounds__(256) void moe_cvt(const float* __restrict__ src,
                                               unsigned short* __restrict__ dst) {
  size_t i = (size_t)blockIdx.x * 256 + threadIdx.x;
  const float4* p = reinterpret_cast<const float4*>(src) + i * 2;
  float4 a = p[0], b = p[1];
  union { unsigned short us[8]; short8 v; } u;
  u.us[0] = f2bf(a.x); u.us[1] = f2bf(a.y); u.us[2] = f2bf(a.z); u.us[3] = f2bf(a.w);
  u.us[4] = f2bf(b.x); u.us[5] = f2bf(b.y); u.us[6] = f2bf(b.z); u.us[7] = f2bf(b.w);
  reinterpret_cast<short8*>(dst)[i] = u.v;
}

// ==== round-9 T4 pipeline: ring-3 LDS, {vmcnt -> barrier -> compute -> stage}, dual-B ====

// GEMM1: g = silu(x@w1^T) * (x@w3^T)   [verbatim round-9 — control]
__global__ __launch_bounds__(256, 2) void moe_gemm1_e(
    const unsigned short* __restrict__ xb, const unsigned short* __restrict__ w1b,
    const unsigned short* __restrict__ w3b, const int* __restrict__ cnt,
    const int* __restrict__ base, const int* __restrict__ pair_token,
    unsigned short* __restrict__ g) {
  int e = blockIdx.z;
  int n_e = cnt[e];
  int rowTile = blockIdx.x;
  if (rowTile * 128 >= n_e) return;
  int colTile = blockIdx.y;

  __shared__ unsigned short lds[3 * 3 * TILE32];   // 72 KB: ring-3 x {A,B1,B3} -> 2 blk/CU

  int tid = threadIdx.x;
  int lane = tid & 63;
  int wv = tid >> 6;
  int wr = wv >> 1, wc = wv & 1;
  int lr = lane & 15;
  int lk = (lane >> 4) * 8;

  int slotP = e * NTOK + rowTile * 128;
  int slotG = base[e] + rowTile * 128;
  const unsigned short* w1e = w1b + (size_t)e * ITR * HID + (size_t)colTile * 128 * HID;
  const unsigned short* w3e = w3b + (size_t)e * ITR * HID + (size_t)colTile * 128 * HID;

  const unsigned short* a_s[2];
  const unsigned short* b1_s[2];
  const unsigned short* b3_s[2];
#pragma unroll
  for (int i = 0; i < 2; ++i) {
    int s = wv * 128 + i * 64 + lane;     // 16B-slot index within 512-slot tile
    int row, c;
    slot_src(s, &row, &c);
    int tok = pair_token[slotP + ((rowTile * 128 + row < n_e) ? row : 0)];
    a_s[i] = xb + (size_t)tok * HID + c * 8;
    b1_s[i] = w1e + (size_t)row * HID + c * 8;
    b3_s[i] = w3e + (size_t)row * HID + c * 8;
  }

  f32x4 acc1[4][4], acc3[4][4];
#pragma unroll
  for (int m = 0; m < 4; ++m)
#pragma unroll
    for (int n = 0; n < 4; ++n) {
      acc1[m][n] = (f32x4){0.f, 0.f, 0.f, 0.f};
      acc3[m][n] = (f32x4){0.f, 0.f, 0.f, 0.f};
    }

#define STAGE1(buf, koff)                                                        \
  do {                                                                           \
    unsigned short* Lb = lds + (buf) * 3 * TILE32 + wv * 1024;                   \
    _Pragma("unroll") for (int i = 0; i < 2; ++i) {                              \
      gload16(a_s[i] + (koff), Lb + i * 512);                                    \
      gload16(b1_s[i] + (koff), Lb + TILE32 + i * 512);                          \
      gload16(b3_s[i] + (koff), Lb + 2 * TILE32 + i * 512);                      \
    }                                                                            \
  } while (0)

  const int nt = HID / BK32;   // 64
  STAGE1(0, 0);
  STAGE1(1, BK32);

  for (int t = 0; t < nt; ++t) {
    if (t + 1 < nt) VMCNT(6); else VMCNT(0);
    BARRIER();

    const unsigned short* A = lds + (t % 3) * 3 * TILE32;
    const unsigned short* B1 = A + TILE32;
    const unsigned short* B3 = A + 2 * TILE32;
    short8 av[4];
#pragma unroll
    for (int m = 0; m < 4; ++m) av[m] = read_frag32(A, wr * 64 + m * 16 + lr, lk);
#pragma unroll
    for (int n = 0; n < 4; ++n) {
      short8 b1v = read_frag32(B1, wc * 64 + n * 16 + lr, lk);
      short8 b3v = read_frag32(B3, wc * 64 + n * 16 + lr, lk);
#pragma unroll
      for (int m = 0; m < 4; ++m) {
        acc1[m][n] = mfma_bf16(av[m], b1v, acc1[m][n]);
        acc3[m][n] = mfma_bf16(av[m], b3v, acc3[m][n]);
      }
    }

    if (t + 2 < nt) STAGE1((t + 2) % 3, (t + 2) * BK32);
  }
#undef STAGE1

#pragma unroll
  for (int m = 0; m < 4; ++m) {
    int rbase = wr * 64 + m * 16 + ((lane >> 4) << 2);
#pragma unroll
    for (int r = 0; r < 4; ++r) {
      int rt = rbase + r;
      if (rowTile * 128 + rt < n_e) {
        unsigned short* grow = g + (size_t)(slotG + rt) * ITR + colTile * 128 + wc * 64;
#pragma unroll
        for (int n = 0; n < 4; ++n) {
          float h1 = acc1[m][n][r], h3 = acc3[m][n][r];
          float sl = h1 / (1.f + __expf(-h1));
          grow[n * 16 + lr] = f2bf(sl * h3);
        }
      }
    }
  }
}

// GEMM2: part[slot] = w * (g[slot] @ w2^T) — dual-B clone of gemm1's geometry:
// 128 rows x 256 cols per block via two 128-col B tiles; 12 reads -> 32 MFMA per wave-K-step
__global__ __launch_bounds__(256, 2) void moe_gemm2_k(
    const unsigned short* __restrict__ g, const unsigned short* __restrict__ w2b,
    const int* __restrict__ cnt, const int* __restrict__ base,
    const float* __restrict__ pair_w, float* __restrict__ part) {
  int e = blockIdx.z;
  int n_e = cnt[e];
  int rowTile = blockIdx.x;
  if (rowTile * 128 >= n_e) return;
  int colTile = blockIdx.y;    // 0..7 (256-col tiles of HID)

  __shared__ unsigned short lds[3 * 3 * TILE32];   // 72 KB: ring-3 x {A,B0,B1} -> 2 blk/CU

  int tid = threadIdx.x;
  int lane = tid & 63;
  int wv = tid >> 6;
  int wr = wv >> 1, wc = wv & 1;
  int lr = lane & 15;
  int lk = (lane >> 4) * 8;

  int slotP = e * NTOK + rowTile * 128;
  int slotG = base[e] + rowTile * 128;
  const unsigned short* w2e = w2b + (size_t)e * HID * ITR + (size_t)colTile * 256 * ITR;

  const unsigned short* a_s[2];
  const unsigned short* b0_s[2];
  const unsigned short* b1_s[2];
#pragma unroll
  for (int i = 0; i < 2; ++i) {
    int s = wv * 128 + i * 64 + lane;
    int row, c;
    slot_src(s, &row, &c);
    int rclamp = (rowTile * 128 + row < n_e) ? row : 0;
    a_s[i] = g + (size_t)(slotG + rclamp) * ITR + c * 8;        // g rows compact -> dense
    b0_s[i] = w2e + (size_t)row * ITR + c * 8;                  // cols [0,128)
    b1_s[i] = w2e + (size_t)(128 + row) * ITR + c * 8;          // cols [128,256)
  }

  f32x4 acc0[4][4], acc1[4][4];
#pragma unroll
  for (int m = 0; m < 4; ++m)
#pragma unroll
    for (int n = 0; n < 4; ++n) {
      acc0[m][n] = (f32x4){0.f, 0.f, 0.f, 0.f};
      acc1[m][n] = (f32x4){0.f, 0.f, 0.f, 0.f};
    }

#define STAGE2(buf, koff)                                                        \
  do {                                                                           \
    unsigned short* Lb = lds + (buf) * 3 * TILE32 + wv * 1024;                   \
    _Pragma("unroll") for (int i = 0; i < 2; ++i) {                              \
      gload16(a_s[i] + (koff), Lb + i * 512);                                    \
      gload16(b0_s[i] + (koff), Lb + TILE32 + i * 512);                          \
      gload16(b1_s[i] + (koff), Lb + 2 * TILE32 + i * 512);                      \
    }                                                                            \
  } while (0)

  const int nt = ITR / BK32;   // 224
  STAGE2(0, 0);
  STAGE2(1, BK32);

  for (int t = 0; t < nt; ++t) {
    if (t + 1 < nt) VMCNT(6); else VMCNT(0);
    BARRIER();

    const unsigned short* A = lds + (t % 3) * 3 * TILE32;
    const unsigned short* B0 = A + TILE32;
    const unsigned short* B1 = A + 2 * TILE32;
    short8 av[4];
#pragma unroll
    for (int m = 0; m < 4; ++m) av[m] = read_frag32(A, wr * 64 + m * 16 + lr, lk);
#pragma unroll
    for (int n = 0; n < 4; ++n) {
      short8 b0v = read_frag32(B0, wc * 64 + n * 16 + lr, lk);
      short8 b1v = read_frag32(B1, wc * 64 + n * 16 + lr, lk);
#pragma unroll
      for (int m = 0; m < 4; ++m) {
        acc0[m][n] = mfma_bf16(av[m], b0v, acc0[m][n]);
        acc1[m][n] = mfma_bf16(av[m], b1v, acc1[m][n]);
      }
    }

    if (t + 2 < nt) STAGE2((t + 2) % 3, (t + 2) * BK32);
  }
#undef STAGE2

#pragma unroll
  for (int m = 0; m < 4; ++m) {
    int rbase = wr * 64 + m * 16 + ((lane >> 4) << 2);
#pragma unroll
    for (int r = 0; r < 4; ++r) {
      int rt = rbase + r;
      if (rowTile * 128 + rt < n_e) {
        float wgt = pair_w[slotP + rt];
        float* prow = part + (size_t)(slotG + rt) * HID + colTile * 256 + wc * 64;
#pragma unroll
        for (int n = 0; n < 4; ++n) {
          prow[n * 16 + lr] = wgt * acc0[m][n][r];
          prow[128 + n * 16 + lr] = wgt * acc1[m][n][r];
        }
      }
    }
  }
}

// ---------------- combine: out[t] = part[slot0] + part[slot1] ----------------
__global__ __launch_bounds__(256) void moe_combine(
    const float* __restrict__ part, const int4* __restrict__ tok_ep,
    const int* __restrict__ base, float* __restrict__ out) {
  int t = blockIdx.x;
  int4 ep = tok_ep[t];
  int s0 = base[ep.x] + ep.z;
  int s1 = base[ep.y] + ep.w;
  const float4* p0 = reinterpret_cast<const float4*>(part + (size_t)s0 * HID);
  const float4* p1 = reinterpret_cast<const float4*>(part + (size_t)s1 * HID);
  float4* o = reinterpret_cast<float4*>(out + (size_t)t * HID);
#pragma unroll
  for (int i = 0; i < 2; ++i) {
    int idx = threadIdx.x + i * 256;    // 512 float4 per row
    float4 a = p0[idx], b = p1[idx];
    o[idx] = make_float4(a.x + b.x, a.y + b.y, a.z + b.z, a.w + b.w);
  }
}

// ================= launch =================

extern "C" void kernel_launch(void* const* d_in, const int* in_sizes, int n_in,
                              void* d_out, int out_size, void* d_ws, size_t ws_size,
                              hipStream_t stream) {
  const float* x = (const float*)d_in[0];
  const float* gate_w = (const float*)d_in[1];
  const float* w1 = (const float*)d_in[2];
  const float* w3 = (const float*)d_in[3];
  const float* w2 = (const float*)d_in[4];
  float* out = (float*)d_out;

  char* ws = (char*)d_ws;
  const size_t WEL = (size_t)NE * ITR * HID;                 // elems per weight tensor
  const size_t G_BYTES = (size_t)NTOK * 2 * ITR * 2;         // 16384 x 7168 bf16
  const size_t XB_BYTES = (size_t)NTOK * HID * 2;
  const size_t PAIR_BYTES = (size_t)NE * NTOK * 4;
  const size_t TOKEP_BYTES = (size_t)NTOK * 16;
  const size_t WB_BYTES = WEL * 2;                           // one bf16 weight tensor

  unsigned short* g = (unsigned short*)ws;
  unsigned short* xb = (unsigned short*)(ws + G_BYTES);
  int* pair_token = (int*)(ws + G_BYTES + XB_BYTES);
  float* pair_w = (float*)(ws + G_BYTES + XB_BYTES + PAIR_BYTES);
  int4* tok_ep = (int4*)(ws + G_BYTES + XB_BYTES + 2 * PAIR_BYTES);
  int* cnt = (int*)(ws + G_BYTES + XB_BYTES + 2 * PAIR_BYTES + TOKEP_BYTES);
  int* base = cnt + NE;
  char* wbase = ws + G_BYTES + XB_BYTES + 2 * PAIR_BYTES + TOKEP_BYTES + 256;
  unsigned short* w1b = (unsigned short*)wbase;
  unsigned short* w3b = (unsigned short*)(wbase + WB_BYTES);
  unsigned short* w2b = (unsigned short*)(wbase + 2 * WB_BYTES);
  float* part = (float*)wbase;   // aliases w1b: dead after gemm1, reused by gemm2

  hipMemsetAsync(cnt, 0, 2 * NE * sizeof(int), stream);

  moe_router<<<NTOK / 4, 256, 0, stream>>>(x, gate_w, cnt, pair_token, pair_w, tok_ep);
  moe_scan<<<1, 64, 0, stream>>>(cnt, base);
  moe_cvt<<<(NTOK * HID) / 2048, 256, 0, stream>>>(x, xb);

  const int WGRID = (int)(WEL / 2048);                       // 57344
  moe_cvt<<<WGRID, 256, 0, stream>>>(w1, w1b);
  moe_cvt<<<WGRID, 256, 0, stream>>>(w3, w3b);
  moe_cvt<<<WGRID, 256, 0, stream>>>(w2, w2b);

  moe_gemm1_e<<<dim3(NTOK / 128, ITR / 128, NE), 256, 0, stream>>>(
      xb, w1b, w3b, cnt, base, pair_token, g);
  moe_gemm2_k<<<dim3(NTOK / 128, HID / 256, NE), 256, 0, stream>>>(
      g, w2b, cnt, base, pair_w, part);
  moe_combine<<<NTOK, 256, 0, stream>>>(part, tok_ep, base, out);
}